// Round 8
// baseline (60.411 us; speedup 1.0000x reference)
//
#include <hip/hip_runtime.h>
#include <hip/hip_bf16.h>

#define NN 8192

typedef float f32x4 __attribute__((ext_vector_type(4)));

__device__ __forceinline__ float lif_activation(
    float I, float x, float vv, float el, float tm)
{
    const float arg   = 12.0f * I / 8192.0f;
    const float Isig  = 1.0f / (1.0f + expf(-arg));
    const float Ifull = Isig + 0.9f * x;
    const float v_next = vv + (el - vv + Ifull * (30.0f - el)) / tm;
    return 1.0f / (1.0f + expf(30.0f - v_next));
}

// Phase 1 v2: sequential-stream GEMV partials.
// Block b owns rows [b*32, b*32+32) -- a fully CONTIGUOUS 1 MB chunk of W --
// and computes partial[b][j] for all 8192 columns j.
// 1024 threads: thread t covers cols t*4..t*4+3 (pass 0) and 4096+t*4.. (pass 1).
// Row-chunk mapping and fmaf order identical to the R7 S=256 split kernel
// -> bit-identical partials/output.
__global__ __launch_bounds__(1024) void lif_gemv_seq(
    const float* __restrict__ g, const float* __restrict__ w,
    float* __restrict__ partial)
{
    const int b  = blockIdx.x;        // 0..255
    const int t  = threadIdx.x;       // 0..1023
    const int r0 = b * 32;

    const float* wp = w + (size_t)r0 * NN + t * 4;
    const float* gp = g + r0;

    f32x4 acc0 = {0.f, 0.f, 0.f, 0.f};
    f32x4 acc1 = {0.f, 0.f, 0.f, 0.f};
    #pragma unroll 4
    for (int i = 0; i < 32; ++i) {
        const float gi = gp[i];                                   // wave-uniform
        const f32x4 w0 = *reinterpret_cast<const f32x4*>(wp + (size_t)i * NN);
        const f32x4 w1 = *reinterpret_cast<const f32x4*>(wp + (size_t)i * NN + 4096);
        acc0.x = fmaf(gi, w0.x, acc0.x);
        acc0.y = fmaf(gi, w0.y, acc0.y);
        acc0.z = fmaf(gi, w0.z, acc0.z);
        acc0.w = fmaf(gi, w0.w, acc0.w);
        acc1.x = fmaf(gi, w1.x, acc1.x);
        acc1.y = fmaf(gi, w1.y, acc1.y);
        acc1.z = fmaf(gi, w1.z, acc1.z);
        acc1.w = fmaf(gi, w1.w, acc1.w);
    }
    *reinterpret_cast<f32x4*>(partial + (size_t)b * NN + t * 4)        = acc0;
    *reinterpret_cast<f32x4*>(partial + (size_t)b * NN + 4096 + t * 4) = acc1;
}

// Phase 2: parallel deterministic reduction + LIF pointwise (R3/R7-proven).
// 256 blocks x 256 threads; block owns 32 columns; 8 split-groups per column.
template <int S>
__global__ __launch_bounds__(256) void lif_pointwise_t(
    const float* __restrict__ partial,
    const float* __restrict__ x_in, const float* __restrict__ v,
    const float* __restrict__ E_L, const float* __restrict__ tau_m,
    float* __restrict__ out)
{
    const int cl = threadIdx.x & 31;   // column within block
    const int kg = threadIdx.x >> 5;   // split group 0..7
    const int j  = blockIdx.x * 32 + cl;
    constexpr int PER = S / 8;

    float acc = 0.f;
    #pragma unroll
    for (int s = 0; s < PER; ++s)      // fixed order: deterministic
        acc += partial[(size_t)(kg * PER + s) * NN + j];

    __shared__ float red[8][32];
    red[kg][cl] = acc;
    __syncthreads();

    if (threadIdx.x < 32) {
        float I = red[0][cl];
        #pragma unroll
        for (int k = 1; k < 8; ++k) I += red[k][cl];   // fixed order
        out[j] = lif_activation(I, x_in[j], v[j], E_L[j], tau_m[j]);
    }
}

// ---------- R7 fallback path (ws too small for 8 MB partials) ----------
__global__ __launch_bounds__(256) void lif_gemv_part_rt(
    const float* __restrict__ g, const float* __restrict__ w,
    float* __restrict__ partial, int rps)
{
    const int col = blockIdx.x * 1024 + threadIdx.x * 4;
    const int s   = blockIdx.y;
    const int r0  = s * rps;
    const float* wp = w + (size_t)r0 * NN + col;
    const float* gp = g + r0;
    f32x4 acc = {0.f, 0.f, 0.f, 0.f};
    #pragma unroll 8
    for (int i = 0; i < rps; ++i) {
        const float gi = gp[i];
        const f32x4 wv = *reinterpret_cast<const f32x4*>(wp + (size_t)i * NN);
        acc.x = fmaf(gi, wv.x, acc.x);
        acc.y = fmaf(gi, wv.y, acc.y);
        acc.z = fmaf(gi, wv.z, acc.z);
        acc.w = fmaf(gi, wv.w, acc.w);
    }
    *reinterpret_cast<f32x4*>(partial + (size_t)s * NN + col) = acc;
}

__global__ __launch_bounds__(256) void lif_pointwise_rt(
    const float* __restrict__ partial, int nsplits,
    const float* __restrict__ x_in, const float* __restrict__ v,
    const float* __restrict__ E_L, const float* __restrict__ tau_m,
    float* __restrict__ out)
{
    const int j = blockIdx.x * blockDim.x + threadIdx.x;
    if (j >= NN) return;
    float I = 0.f;
    for (int s = 0; s < nsplits; ++s)
        I += partial[(size_t)s * NN + j];
    out[j] = lif_activation(I, x_in[j], v[j], E_L[j], tau_m[j]);
}
// -----------------------------------------------------------------------

extern "C" void kernel_launch(void* const* d_in, const int* in_sizes, int n_in,
                              void* d_out, int out_size, void* d_ws, size_t ws_size,
                              hipStream_t stream) {
    const float* x_in  = (const float*)d_in[0];
    const float* v     = (const float*)d_in[1];
    const float* g     = (const float*)d_in[2];
    const float* w     = (const float*)d_in[3];
    const float* E_L   = (const float*)d_in[4];
    const float* tau_m = (const float*)d_in[5];
    // d_in[6] = tau_g, unused by the reference
    float* out     = (float*)d_out;
    float* partial = (float*)d_ws;

    constexpr size_t SEQ_BYTES = (size_t)256 * NN * sizeof(float);   // 8 MB

    if (ws_size >= SEQ_BYTES) {
        lif_gemv_seq<<<256, 1024, 0, stream>>>(g, w, partial);
        lif_pointwise_t<256><<<NN / 32, 256, 0, stream>>>(partial, x_in, v, E_L, tau_m, out);
    } else {
        int S = 128;
        while (S > 1 && (size_t)S * NN * sizeof(float) > ws_size) S >>= 1;
        dim3 grid1(NN / 1024, S);
        lif_gemv_part_rt<<<grid1, 256, 0, stream>>>(g, w, partial, NN / S);
        switch (S) {
            case 128: lif_pointwise_t<128><<<NN / 32, 256, 0, stream>>>(partial, x_in, v, E_L, tau_m, out); break;
            case  64: lif_pointwise_t< 64><<<NN / 32, 256, 0, stream>>>(partial, x_in, v, E_L, tau_m, out); break;
            case  32: lif_pointwise_t< 32><<<NN / 32, 256, 0, stream>>>(partial, x_in, v, E_L, tau_m, out); break;
            default:  lif_pointwise_rt<<<NN / 256, 256, 0, stream>>>(partial, S, x_in, v, E_L, tau_m, out); break;
        }
    }
}

// Round 9
// 52.802 us; speedup vs baseline: 1.1441x; 1.1441x over previous
//
#include <hip/hip_runtime.h>
#include <hip/hip_bf16.h>

#define NN 8192

typedef float f32x4 __attribute__((ext_vector_type(4)));

__device__ __forceinline__ float lif_activation(
    float I, float x, float vv, float el, float tm)
{
    const float arg   = 12.0f * I / 8192.0f;
    const float Isig  = 1.0f / (1.0f + expf(-arg));
    const float Ifull = Isig + 0.9f * x;
    const float v_next = vv + (el - vv + Ifull * (30.0f - el)) / tm;
    return 1.0f / (1.0f + expf(30.0f - v_next));
}

// Phase 1: split-K GEMV partials, XCD-balanced grid.
// Grid (S, 8): blockIdx.x = row split s (0..S-1), blockIdx.y = column tile (0..7).
// Linear block id = s + S*tile -> XCD = id % 8 = s % 8, so every XCD reads
// full-width rows (all 8 column tiles) instead of one column stripe
// (R7 had grid (8,S): XCD == column tile -> per-XCD channel hot-spotting).
// fmaf order identical to R7 -> bit-identical output.
__global__ __launch_bounds__(256) void lif_gemv_part(
    const float* __restrict__ g, const float* __restrict__ w,
    float* __restrict__ partial, int rows_per_split)
{
    const int col = blockIdx.y * 1024 + threadIdx.x * 4;
    const int s   = blockIdx.x;
    const int r0  = s * rows_per_split;

    const float* wp = w + (size_t)r0 * NN + col;
    const float* gp = g + r0;

    f32x4 acc = {0.f, 0.f, 0.f, 0.f};
    #pragma unroll 8
    for (int i = 0; i < rows_per_split; ++i) {
        const float gi = gp[i];                       // wave-uniform scalar load
        const f32x4 wv = *reinterpret_cast<const f32x4*>(wp + (size_t)i * NN);
        acc.x = fmaf(gi, wv.x, acc.x);
        acc.y = fmaf(gi, wv.y, acc.y);
        acc.z = fmaf(gi, wv.z, acc.z);
        acc.w = fmaf(gi, wv.w, acc.w);
    }
    *reinterpret_cast<f32x4*>(partial + (size_t)s * NN + col) = acc;
}

// Phase 2: parallel deterministic reduction + LIF pointwise (proven).
// 256 blocks x 256 threads; block owns 32 columns; 8 split-groups per column.
template <int S>
__global__ __launch_bounds__(256) void lif_pointwise_t(
    const float* __restrict__ partial,
    const float* __restrict__ x_in, const float* __restrict__ v,
    const float* __restrict__ E_L, const float* __restrict__ tau_m,
    float* __restrict__ out)
{
    const int cl = threadIdx.x & 31;   // column within block
    const int kg = threadIdx.x >> 5;   // split group 0..7
    const int j  = blockIdx.x * 32 + cl;
    constexpr int PER = S / 8;

    float acc = 0.f;
    #pragma unroll
    for (int s = 0; s < PER; ++s)      // fixed order: deterministic
        acc += partial[(size_t)(kg * PER + s) * NN + j];

    __shared__ float red[8][32];
    red[kg][cl] = acc;
    __syncthreads();

    if (threadIdx.x < 32) {
        float I = red[0][cl];
        #pragma unroll
        for (int k = 1; k < 8; ++k) I += red[k][cl];   // fixed order
        out[j] = lif_activation(I, x_in[j], v[j], E_L[j], tau_m[j]);
    }
}

// Runtime fallback (any nsplits).
__global__ __launch_bounds__(256) void lif_pointwise_rt(
    const float* __restrict__ partial, int nsplits,
    const float* __restrict__ x_in, const float* __restrict__ v,
    const float* __restrict__ E_L, const float* __restrict__ tau_m,
    float* __restrict__ out)
{
    const int j = blockIdx.x * blockDim.x + threadIdx.x;
    if (j >= NN) return;
    float I = 0.f;
    for (int s = 0; s < nsplits; ++s)
        I += partial[(size_t)s * NN + j];
    out[j] = lif_activation(I, x_in[j], v[j], E_L[j], tau_m[j]);
}

extern "C" void kernel_launch(void* const* d_in, const int* in_sizes, int n_in,
                              void* d_out, int out_size, void* d_ws, size_t ws_size,
                              hipStream_t stream) {
    const float* x_in  = (const float*)d_in[0];
    const float* v     = (const float*)d_in[1];
    const float* g     = (const float*)d_in[2];
    const float* w     = (const float*)d_in[3];
    const float* E_L   = (const float*)d_in[4];
    const float* tau_m = (const float*)d_in[5];
    // d_in[6] = tau_g, unused by the reference
    float* out     = (float*)d_out;
    float* partial = (float*)d_ws;

    int S = 256;
    while (S > 1 && (size_t)S * NN * sizeof(float) > ws_size) S >>= 1;

    dim3 grid1(S, NN / 1024);   // x = split (XCD-spread), y = column tile
    lif_gemv_part<<<grid1, 256, 0, stream>>>(g, w, partial, NN / S);

    switch (S) {
        case 256: lif_pointwise_t<256><<<NN / 32, 256, 0, stream>>>(partial, x_in, v, E_L, tau_m, out); break;
        case 128: lif_pointwise_t<128><<<NN / 32, 256, 0, stream>>>(partial, x_in, v, E_L, tau_m, out); break;
        case  64: lif_pointwise_t< 64><<<NN / 32, 256, 0, stream>>>(partial, x_in, v, E_L, tau_m, out); break;
        case  32: lif_pointwise_t< 32><<<NN / 32, 256, 0, stream>>>(partial, x_in, v, E_L, tau_m, out); break;
        default:  lif_pointwise_rt<<<NN / 256, 256, 0, stream>>>(partial, S, x_in, v, E_L, tau_m, out); break;
    }
}

// Round 10
// 49.993 us; speedup vs baseline: 1.2084x; 1.0562x over previous
//
#include <hip/hip_runtime.h>
#include <hip/hip_bf16.h>

#define NN 8192

typedef float f32x4 __attribute__((ext_vector_type(4)));

__device__ __forceinline__ float lif_activation(
    float I, float x, float vv, float el, float tm)
{
    const float arg   = 12.0f * I / 8192.0f;
    const float Isig  = 1.0f / (1.0f + expf(-arg));
    const float Ifull = Isig + 0.9f * x;
    const float v_next = vv + (el - vv + Ifull * (30.0f - el)) / tm;
    return 1.0f / (1.0f + expf(30.0f - v_next));
}

// Phase 1: split-K GEMV partials — R7 config (grid (8,S), best at 49.2us),
// single change: unroll 8 -> 16 (deeper vmem pipeline, 16 loads in flight/wave).
// fmaf order identical -> bit-identical output.
__global__ __launch_bounds__(256) void lif_gemv_part(
    const float* __restrict__ g, const float* __restrict__ w,
    float* __restrict__ partial, int rows_per_split)
{
    const int col = blockIdx.x * 1024 + threadIdx.x * 4;
    const int s   = blockIdx.y;
    const int r0  = s * rows_per_split;

    const float* wp = w + (size_t)r0 * NN + col;
    const float* gp = g + r0;

    f32x4 acc = {0.f, 0.f, 0.f, 0.f};
    #pragma unroll 16
    for (int i = 0; i < rows_per_split; ++i) {
        const float gi = gp[i];                       // wave-uniform scalar load
        const f32x4 wv = *reinterpret_cast<const f32x4*>(wp + (size_t)i * NN);
        acc.x = fmaf(gi, wv.x, acc.x);
        acc.y = fmaf(gi, wv.y, acc.y);
        acc.z = fmaf(gi, wv.z, acc.z);
        acc.w = fmaf(gi, wv.w, acc.w);
    }
    *reinterpret_cast<f32x4*>(partial + (size_t)s * NN + col) = acc;
}

// Phase 2: parallel deterministic reduction + LIF pointwise (proven).
template <int S>
__global__ __launch_bounds__(256) void lif_pointwise_t(
    const float* __restrict__ partial,
    const float* __restrict__ x_in, const float* __restrict__ v,
    const float* __restrict__ E_L, const float* __restrict__ tau_m,
    float* __restrict__ out)
{
    const int cl = threadIdx.x & 31;   // column within block
    const int kg = threadIdx.x >> 5;   // split group 0..7
    const int j  = blockIdx.x * 32 + cl;
    constexpr int PER = S / 8;

    float acc = 0.f;
    #pragma unroll
    for (int s = 0; s < PER; ++s)      // fixed order: deterministic
        acc += partial[(size_t)(kg * PER + s) * NN + j];

    __shared__ float red[8][32];
    red[kg][cl] = acc;
    __syncthreads();

    if (threadIdx.x < 32) {
        float I = red[0][cl];
        #pragma unroll
        for (int k = 1; k < 8; ++k) I += red[k][cl];   // fixed order
        out[j] = lif_activation(I, x_in[j], v[j], E_L[j], tau_m[j]);
    }
}

// Runtime fallback (any nsplits).
__global__ __launch_bounds__(256) void lif_pointwise_rt(
    const float* __restrict__ partial, int nsplits,
    const float* __restrict__ x_in, const float* __restrict__ v,
    const float* __restrict__ E_L, const float* __restrict__ tau_m,
    float* __restrict__ out)
{
    const int j = blockIdx.x * blockDim.x + threadIdx.x;
    if (j >= NN) return;
    float I = 0.f;
    for (int s = 0; s < nsplits; ++s)
        I += partial[(size_t)s * NN + j];
    out[j] = lif_activation(I, x_in[j], v[j], E_L[j], tau_m[j]);
}

extern "C" void kernel_launch(void* const* d_in, const int* in_sizes, int n_in,
                              void* d_out, int out_size, void* d_ws, size_t ws_size,
                              hipStream_t stream) {
    const float* x_in  = (const float*)d_in[0];
    const float* v     = (const float*)d_in[1];
    const float* g     = (const float*)d_in[2];
    const float* w     = (const float*)d_in[3];
    const float* E_L   = (const float*)d_in[4];
    const float* tau_m = (const float*)d_in[5];
    // d_in[6] = tau_g, unused by the reference
    float* out     = (float*)d_out;
    float* partial = (float*)d_ws;

    int S = 256;
    while (S > 1 && (size_t)S * NN * sizeof(float) > ws_size) S >>= 1;

    dim3 grid1(NN / 1024, S);   // R7 layout: x = column tile, y = split
    lif_gemv_part<<<grid1, 256, 0, stream>>>(g, w, partial, NN / S);

    switch (S) {
        case 256: lif_pointwise_t<256><<<NN / 32, 256, 0, stream>>>(partial, x_in, v, E_L, tau_m, out); break;
        case 128: lif_pointwise_t<128><<<NN / 32, 256, 0, stream>>>(partial, x_in, v, E_L, tau_m, out); break;
        case  64: lif_pointwise_t< 64><<<NN / 32, 256, 0, stream>>>(partial, x_in, v, E_L, tau_m, out); break;
        case  32: lif_pointwise_t< 32><<<NN / 32, 256, 0, stream>>>(partial, x_in, v, E_L, tau_m, out); break;
        default:  lif_pointwise_rt<<<NN / 256, 256, 0, stream>>>(partial, S, x_in, v, E_L, tau_m, out); break;
    }
}